// Round 1
// baseline (1633.816 us; speedup 1.0000x reference)
//
#include <hip/hip_runtime.h>

typedef unsigned int uint_t;
typedef _Float16 h2 __attribute__((ext_vector_type(2)));

#define NPTS 1024
#define DIM  128
#define NH2  64          // half2 words per point
#define NW   16          // waves per block

__device__ __forceinline__ float dot2f(uint_t a, uint_t b, float c) {
#if __has_builtin(__builtin_amdgcn_fdot2)
    return __builtin_amdgcn_fdot2(__builtin_bit_cast(h2, a),
                                  __builtin_bit_cast(h2, b), c, false);
#else
    h2 ha = __builtin_bit_cast(h2, a);
    h2 hb = __builtin_bit_cast(h2, b);
    c += (float)ha[0] * (float)hb[0];
    c += (float)ha[1] * (float)hb[1];
    return c;
#endif
}

__device__ __forceinline__ uint_t umin_u(uint_t a, uint_t b) { return a < b ? a : b; }

// One block (1024 threads = 16 waves) per sample. Thread t owns point t:
// 128 dims packed as 64 half2 in VGPRs. Prim's MST, 1023 sequential steps.
__global__ __launch_bounds__(1024)
void prim_mst_kernel(const float* __restrict__ reps, float* __restrict__ out,
                     float scale) {
    const int s    = blockIdx.x;
    const int t    = threadIdx.x;
    const int lane = t & 63;
    const int wave = t >> 6;

    __shared__ uint4  sbc[NH2 / 4];   // broadcast coords of last-visited point
    __shared__ float  sbn;            // its norm
    __shared__ float  sdeath;         // exact d^2 of selected MST edge
    __shared__ uint_t skey;           // block argmin packed key
    __shared__ uint_t warr[NW];       // per-wave argmin keys

    // ---- load my point, quantize to fp16, norm of quantized coords ----
    uint_t cx[NH2];
    float  nrm = 0.f;
    const float4* src =
        (const float4*)(reps + (size_t)s * (NPTS * DIM) + (size_t)t * DIM);
#pragma unroll
    for (int k = 0; k < 32; ++k) {
        float4 v = src[k];
        h2 a; a[0] = (_Float16)v.x; a[1] = (_Float16)v.y;
        h2 b; b[0] = (_Float16)v.z; b[1] = (_Float16)v.w;
        cx[2 * k]     = __builtin_bit_cast(uint_t, a);
        cx[2 * k + 1] = __builtin_bit_cast(uint_t, b);
        nrm = dot2f(cx[2 * k], cx[2 * k], nrm);
        nrm = dot2f(cx[2 * k + 1], cx[2 * k + 1], nrm);
    }

    // ---- seed: point 0 is visited first ----
    if (t == 0) {
#pragma unroll
        for (int k = 0; k < NH2 / 4; ++k)
            sbc[k] = make_uint4(cx[4 * k], cx[4 * k + 1], cx[4 * k + 2], cx[4 * k + 3]);
        sbn = nrm;
    }
    __syncthreads();

    float mind    = 3.0e38f;
    bool  visited = (t == 0);
    float acc_sum = 0.f;

    for (int it = 0; it < NPTS - 1; ++it) {
        // (a) distance to last-visited point, min-update
        float a0 = 0.f, a1 = 0.f, a2 = 0.f, a3 = 0.f;
#pragma unroll
        for (int k = 0; k < NH2 / 4; ++k) {
            uint4 q = sbc[k];   // LDS broadcast read (all lanes same addr)
            a0 = dot2f(cx[4 * k + 0], q.x, a0);
            a1 = dot2f(cx[4 * k + 1], q.y, a1);
            a2 = dot2f(cx[4 * k + 2], q.z, a2);
            a3 = dot2f(cx[4 * k + 3], q.w, a3);
        }
        float d2 = sbn + nrm - 2.f * ((a0 + a1) + (a2 + a3));
        d2 = fmaxf(d2, 0.f);
        if (!visited) mind = fminf(mind, d2);

        // (b) block argmin over masked mindist, key = dist bits | tid
        uint_t key = visited
                   ? 0xFFFFFFFFu
                   : ((__float_as_uint(mind) & 0xFFFFFC00u) | (uint_t)t);
#pragma unroll
        for (int m = 32; m >= 1; m >>= 1)
            key = umin_u(key, (uint_t)__shfl_xor((int)key, m, 64));
        if (lane == 0) warr[wave] = key;
        __syncthreads();
        if (wave == 0) {
            uint_t k2 = (lane < NW) ? warr[lane] : 0xFFFFFFFFu;
#pragma unroll
            for (int m = 8; m >= 1; m >>= 1)
                k2 = umin_u(k2, (uint_t)__shfl_xor((int)k2, m, 16));
            if (lane == 0) skey = k2;
        }
        __syncthreads();

        // (c) winner publishes exact death + its coords for next step
        const int j = (int)(skey & 0x3FFu);
        if (t == j) {
#pragma unroll
            for (int k = 0; k < NH2 / 4; ++k)
                sbc[k] = make_uint4(cx[4 * k], cx[4 * k + 1], cx[4 * k + 2], cx[4 * k + 3]);
            sbn     = nrm;
            sdeath  = mind;
            visited = true;
        }
        __syncthreads();
        if (t == 0) acc_sum += sqrtf(sdeath);
    }

    if (t == 0) atomicAdd(out, acc_sum * scale);
}

extern "C" void kernel_launch(void* const* d_in, const int* in_sizes, int n_in,
                              void* d_out, int out_size, void* d_ws, size_t ws_size,
                              hipStream_t stream) {
    const float* reps = (const float*)d_in[0];
    float*       out  = (float*)d_out;
    const int b = in_sizes[0] / (NPTS * DIM);   // batch size (128)

    // loss = sum_s( mean_s ) / (b * 2); mean_s = sum_deaths / (NPTS-1)
    const float scale = 1.0f / ((float)(NPTS - 1) * (float)b * 2.0f);

    hipMemsetAsync(out, 0, sizeof(float), stream);
    prim_mst_kernel<<<dim3(b), dim3(1024), 0, stream>>>(reps, out, scale);
}